// Round 1
// baseline (31289.450 us; speedup 1.0000x reference)
//
#include <hip/hip_runtime.h>
#include <math.h>

#define SEQ   2048
#define BATCH 64
#define IN    256
#define HID   256

// ---------------------------------------------------------------------------
// Kernel A: input projections.
//   xz[s,b,o] = sum_i x[s,b,i] * Wz[o,i] + bz[o]   -> d_ws   (fp32, S*B*H)
//   xh[s,b,o] = sum_i x[s,b,i] * Wh[o,i] + bh[o]   -> d_out  (fp32, S*B*H)
// Grid: (S*B)/32 WGs, 256 threads. Thread `tid` owns output column `tid` of
// BOTH Wz and Wh for a 32-row tile. x row data is read as float4 broadcasts
// (same address across all lanes -> 1 L1 line per instruction); W rows are
// per-thread streams (L1/L2 resident, 512 KB total, reused by all 4096 WGs).
// ---------------------------------------------------------------------------
__global__ __launch_bounds__(256) void proj_kernel(
    const float* __restrict__ x,
    const float* __restrict__ Wz, const float* __restrict__ bz,
    const float* __restrict__ Wh, const float* __restrict__ bh,
    float* __restrict__ xz_out,   // d_ws
    float* __restrict__ xh_out)   // d_out (outputs region)
{
    const int tid  = threadIdx.x;        // 0..255 = output column
    const int row0 = blockIdx.x * 32;    // first of 32 rows (flattened s*B+b)

    float accz[32];
    float acch[32];
    const float bzv = bz[tid];
    const float bhv = bh[tid];
#pragma unroll
    for (int r = 0; r < 32; ++r) { accz[r] = bzv; acch[r] = bhv; }

    const float* wzr = Wz + tid * IN;
    const float* whr = Wh + tid * IN;

    for (int k4 = 0; k4 < IN / 4; ++k4) {
        const float4 wz = *reinterpret_cast<const float4*>(wzr + k4 * 4);
        const float4 wh = *reinterpret_cast<const float4*>(whr + k4 * 4);
#pragma unroll
        for (int r = 0; r < 32; ++r) {
            const float4 xv = *reinterpret_cast<const float4*>(
                x + (size_t)(row0 + r) * IN + k4 * 4);
            accz[r] += xv.x * wz.x + xv.y * wz.y + xv.z * wz.z + xv.w * wz.w;
            acch[r] += xv.x * wh.x + xv.y * wh.y + xv.z * wh.z + xv.w * wh.w;
        }
    }

#pragma unroll
    for (int r = 0; r < 32; ++r) {
        const size_t o = (size_t)(row0 + r) * HID + tid;
        xz_out[o] = accz[r];
        xh_out[o] = acch[r];
    }
}

// ---------------------------------------------------------------------------
// Kernel B: sequential GRU-lite recurrence. One WG per batch element (64 WGs,
// 256 threads). h lives in LDS; thread `tid` owns output row `tid` of Uz/Uh
// (streamed from L2 each step, ~512 KB/WG/step). xh was staged into d_out and
// is overwritten in-place by h_new (read-before-write, same thread).
// ---------------------------------------------------------------------------
__global__ __launch_bounds__(256) void rec_kernel(
    const float* __restrict__ hidden0,
    const float* __restrict__ Uz, const float* __restrict__ cz,
    const float* __restrict__ Uh, const float* __restrict__ ch,
    const float* __restrict__ xz_in,  // d_ws
    float* __restrict__ out,          // d_out: [SEQ*BATCH*HID] = xh in, h out
    float* __restrict__ h_final)      // d_out + SEQ*BATCH*HID
{
    const int b   = blockIdx.x;   // batch element
    const int tid = threadIdx.x;  // hidden unit

    __shared__ float h_s[HID];
    h_s[tid] = hidden0[b * HID + tid];
    __syncthreads();

    const float czv = cz[tid];
    const float chv = ch[tid];
    const float* uzr = Uz + tid * HID;
    const float* uhr = Uh + tid * HID;

    float hnew = h_s[tid];
    for (int t = 0; t < SEQ; ++t) {
        const size_t base = ((size_t)t * BATCH + b) * HID + tid;
        float accz = xz_in[base] + czv;
        float acch = out[base]   + chv;   // xh staged here

#pragma unroll 16
        for (int k4 = 0; k4 < HID / 4; ++k4) {
            const float4 hv = *reinterpret_cast<const float4*>(&h_s[k4 * 4]);
            const float4 uz = *reinterpret_cast<const float4*>(uzr + k4 * 4);
            const float4 uh = *reinterpret_cast<const float4*>(uhr + k4 * 4);
            accz += hv.x * uz.x + hv.y * uz.y + hv.z * uz.z + hv.w * uz.w;
            acch += hv.x * uh.x + hv.y * uh.y + hv.z * uh.z + hv.w * uh.w;
        }

        const float hprev = h_s[tid];
        const float z  = 1.0f / (1.0f + __expf(-accz));
        const float ht = tanhf(acch);
        hnew = (1.0f - z) * hprev + z * ht;

        __syncthreads();          // all matvec reads of h_s done
        h_s[tid] = hnew;
        out[base] = hnew;         // overwrites staged xh (already consumed)
        __syncthreads();          // h_s update visible before next step reads
    }

    h_final[b * HID + tid] = hnew;
}

extern "C" void kernel_launch(void* const* d_in, const int* in_sizes, int n_in,
                              void* d_out, int out_size, void* d_ws, size_t ws_size,
                              hipStream_t stream) {
    const float* x      = (const float*)d_in[0];
    const float* hidden = (const float*)d_in[1];
    const float* Wz     = (const float*)d_in[2];
    const float* bz     = (const float*)d_in[3];
    const float* Uz     = (const float*)d_in[4];
    const float* cz     = (const float*)d_in[5];
    const float* Wh     = (const float*)d_in[6];
    const float* bh     = (const float*)d_in[7];
    const float* Uh     = (const float*)d_in[8];
    const float* ch     = (const float*)d_in[9];

    float* out     = (float*)d_out;                        // [SEQ*BATCH*HID]
    float* h_final = out + (size_t)SEQ * BATCH * HID;      // [BATCH*HID]
    float* xz_ws   = (float*)d_ws;                         // needs 128 MiB

    // Projections: xz -> ws, xh -> d_out (consumed in-place by recurrence).
    proj_kernel<<<(SEQ * BATCH) / 32, 256, 0, stream>>>(
        x, Wz, bz, Wh, bh, xz_ws, out);

    // Sequential scan: one WG per batch element.
    rec_kernel<<<BATCH, 256, 0, stream>>>(
        hidden, Uz, cz, Uh, ch, xz_ws, out, h_final);
}

// Round 2
// 3342.541 us; speedup vs baseline: 9.3610x; 9.3610x over previous
//
#include <hip/hip_runtime.h>
#include <math.h>

#define SEQ   2048
#define BATCH 64
#define IN    256
#define HID   256

typedef _Float16 hf2 __attribute__((ext_vector_type(2)));
typedef _Float16 hf8 __attribute__((ext_vector_type(8)));

static __device__ __forceinline__ hf2 make_hf2(float a, float b) {
    hf2 r;
    r.x = (_Float16)a;
    r.y = (_Float16)b;
    return r;
}

// fp16 x fp16 -> fp32 accumulate, 2-way dot.
static __device__ __forceinline__ float dot2(hf2 a, hf2 b, float c) {
#if __has_builtin(__builtin_amdgcn_fdot2)
    return __builtin_amdgcn_fdot2(a, b, c, false);
#else
    return c + (float)a.x * (float)b.x + (float)a.y * (float)b.y;
#endif
}

// ---------------------------------------------------------------------------
// Kernel A: input projections (unchanged from R1, fp32).
//   xz[s,b,o] -> d_ws ; xh[s,b,o] -> d_out (consumed in place by rec_kernel)
// ---------------------------------------------------------------------------
__global__ __launch_bounds__(256) void proj_kernel(
    const float* __restrict__ x,
    const float* __restrict__ Wz, const float* __restrict__ bz,
    const float* __restrict__ Wh, const float* __restrict__ bh,
    float* __restrict__ xz_out,   // d_ws
    float* __restrict__ xh_out)   // d_out (outputs region)
{
    const int tid  = threadIdx.x;        // 0..255 = output column
    const int row0 = blockIdx.x * 32;    // first of 32 rows (flattened s*B+b)

    float accz[32];
    float acch[32];
    const float bzv = bz[tid];
    const float bhv = bh[tid];
#pragma unroll
    for (int r = 0; r < 32; ++r) { accz[r] = bzv; acch[r] = bhv; }

    const float* wzr = Wz + tid * IN;
    const float* whr = Wh + tid * IN;

    for (int k4 = 0; k4 < IN / 4; ++k4) {
        const float4 wz = *reinterpret_cast<const float4*>(wzr + k4 * 4);
        const float4 wh = *reinterpret_cast<const float4*>(whr + k4 * 4);
#pragma unroll
        for (int r = 0; r < 32; ++r) {
            const float4 xv = *reinterpret_cast<const float4*>(
                x + (size_t)(row0 + r) * IN + k4 * 4);
            accz[r] += xv.x * wz.x + xv.y * wz.y + xv.z * wz.z + xv.w * wz.w;
            acch[r] += xv.x * wh.x + xv.y * wh.y + xv.z * wh.z + xv.w * wh.w;
        }
    }

#pragma unroll
    for (int r = 0; r < 32; ++r) {
        const size_t o = (size_t)(row0 + r) * HID + tid;
        xz_out[o] = accz[r];
        xh_out[o] = acch[r];
    }
}

// ---------------------------------------------------------------------------
// Kernel B: recurrence with REGISTER-RESIDENT U (fp16 storage, fp32 accumulate
// via v_dot2_f32_f16). One WG of 1024 threads per batch element:
//   thread (o = tid>>2, q = tid&3) owns Uz[o, 64q:64q+64] and Uh[o, ...]
//   as 64 packed half2 VGPRs. h state: fp32 in leader (q==0) register — the
//   recurrence h_new = (1-z)h + z*h~ is EXACT fp32; only the matvec operand
//   h is rounded to fp16 (|h| < 1, |U| < 1/16 -> error ~5e-4/step preact).
// h published to LDS as fp16, double-buffered, +8-half skew per 64-slice so
// the 4 q-slices start in different banks (else 4-way conflict: 128 B = one
// full bank stride).
// Per step: 8x ds_read_b128 (16-lane broadcast) + 64 dot2 + 2x shfl_xor
// reduce + leader epilogue + 1 barrier. xz/xh loads issued at step start,
// consumed after the matvec -> HBM latency hidden under compute.
// ---------------------------------------------------------------------------
__global__ __launch_bounds__(1024) void rec_kernel(
    const float* __restrict__ hidden0,
    const float* __restrict__ Uz, const float* __restrict__ cz,
    const float* __restrict__ Uh, const float* __restrict__ ch,
    const float* __restrict__ xz_in,  // d_ws
    float* __restrict__ out,          // d_out: [SEQ*BATCH*HID] xh in, h out
    float* __restrict__ h_final)      // d_out + SEQ*BATCH*HID
{
    const int b   = blockIdx.x;
    const int tid = threadIdx.x;
    const int o   = tid >> 2;   // output index 0..255
    const int q   = tid & 3;    // k-slice 0..3

    // [2] double buffer; 64-slice q starts at q*72 halves (skew 8 halves/q).
    __shared__ __align__(16) _Float16 h_h[2][HID + 24];

    // ---- hoist U into registers (one time) ----
    hf2 uz[32], uh[32];
    {
        const float* uzp = Uz + o * HID + q * 64;
        const float* uhp = Uh + o * HID + q * 64;
#pragma unroll
        for (int i = 0; i < 16; ++i) {
            const float4 a = *reinterpret_cast<const float4*>(uzp + i * 4);
            const float4 c = *reinterpret_cast<const float4*>(uhp + i * 4);
            uz[2 * i]     = make_hf2(a.x, a.y);
            uz[2 * i + 1] = make_hf2(a.z, a.w);
            uh[2 * i]     = make_hf2(c.x, c.y);
            uh[2 * i + 1] = make_hf2(c.z, c.w);
        }
    }

    const bool leader = (q == 0);
    float hprev = 0.0f, czv = 0.0f, chv = 0.0f;
    if (leader) {
        hprev = hidden0[b * HID + o];
        czv   = cz[o];
        chv   = ch[o];
        h_h[0][o + (o >> 6) * 8] = (_Float16)hprev;
    }
    __syncthreads();

    int cur = 0;
    for (int t = 0; t < SEQ; ++t) {
        const size_t base = ((size_t)t * BATCH + b) * HID + o;
        float xzv = 0.0f, xhv = 0.0f;
        if (leader) {
            xzv = xz_in[base];   // issued now, consumed after matvec
            xhv = out[base];     // staged xh
        }

        const _Float16* hp = &h_h[cur][q * 72];
        float accz = 0.0f, acch = 0.0f;
#pragma unroll
        for (int c8 = 0; c8 < 8; ++c8) {
            const hf8 hv = *reinterpret_cast<const hf8*>(hp + c8 * 8);
            const hf2 h0 = make_hf2((float)hv[0], (float)hv[1]);
            const hf2 h1 = make_hf2((float)hv[2], (float)hv[3]);
            const hf2 h2 = make_hf2((float)hv[4], (float)hv[5]);
            const hf2 h3 = make_hf2((float)hv[6], (float)hv[7]);
            accz = dot2(h0, uz[4 * c8 + 0], accz);
            accz = dot2(h1, uz[4 * c8 + 1], accz);
            accz = dot2(h2, uz[4 * c8 + 2], accz);
            accz = dot2(h3, uz[4 * c8 + 3], accz);
            acch = dot2(h0, uh[4 * c8 + 0], acch);
            acch = dot2(h1, uh[4 * c8 + 1], acch);
            acch = dot2(h2, uh[4 * c8 + 2], acch);
            acch = dot2(h3, uh[4 * c8 + 3], acch);
        }

        // reduce over the 4 q-slices (adjacent lanes)
        accz += __shfl_xor(accz, 1);
        accz += __shfl_xor(accz, 2);
        acch += __shfl_xor(acch, 1);
        acch += __shfl_xor(acch, 2);

        if (leader) {
            const float az = accz + xzv + czv;
            const float ah = acch + xhv + chv;
            const float z  = 1.0f / (1.0f + __expf(-az));
            const float ht = tanhf(ah);
            const float hnew = (1.0f - z) * hprev + z * ht;
            hprev = hnew;
            out[base] = hnew;                               // fp32 exact out
            h_h[cur ^ 1][o + (o >> 6) * 8] = (_Float16)hnew; // fp16 operand
        }
        __syncthreads();   // publish h_h[cur^1]; reads of h_h[cur] are done
        cur ^= 1;
    }

    if (leader) h_final[b * HID + o] = hprev;
}

extern "C" void kernel_launch(void* const* d_in, const int* in_sizes, int n_in,
                              void* d_out, int out_size, void* d_ws, size_t ws_size,
                              hipStream_t stream) {
    const float* x      = (const float*)d_in[0];
    const float* hidden = (const float*)d_in[1];
    const float* Wz     = (const float*)d_in[2];
    const float* bz     = (const float*)d_in[3];
    const float* Uz     = (const float*)d_in[4];
    const float* cz     = (const float*)d_in[5];
    const float* Wh     = (const float*)d_in[6];
    const float* bh     = (const float*)d_in[7];
    const float* Uh     = (const float*)d_in[8];
    const float* ch     = (const float*)d_in[9];

    float* out     = (float*)d_out;                        // [SEQ*BATCH*HID]
    float* h_final = out + (size_t)SEQ * BATCH * HID;      // [BATCH*HID]
    float* xz_ws   = (float*)d_ws;                         // 128 MiB

    proj_kernel<<<(SEQ * BATCH) / 32, 256, 0, stream>>>(
        x, Wz, bz, Wh, bh, xz_ws, out);

    rec_kernel<<<BATCH, 1024, 0, stream>>>(
        hidden, Uz, cz, Uh, ch, xz_ws, out, h_final);
}

// Round 3
// 2812.954 us; speedup vs baseline: 11.1233x; 1.1883x over previous
//
#include <hip/hip_runtime.h>
#include <math.h>

#define SEQ   2048
#define BATCH 64
#define IN    256
#define HID   256

typedef _Float16 hf2 __attribute__((ext_vector_type(2)));
typedef _Float16 hf8 __attribute__((ext_vector_type(8)));

static __device__ __forceinline__ float dot2(hf2 a, hf2 b, float c) {
#if __has_builtin(__builtin_amdgcn_fdot2)
    return __builtin_amdgcn_fdot2(a, b, c, false);
#else
    return fmaf((float)a.x, (float)b.x, fmaf((float)a.y, (float)b.y, c));
#endif
}

static __device__ __forceinline__ float fast_sigmoid(float x) {
    return __builtin_amdgcn_rcpf(1.0f + __expf(-x));
}

static __device__ __forceinline__ float fast_tanh(float x) {
    const float e = __expf(-2.0f * fabsf(x));
    const float t = (1.0f - e) * __builtin_amdgcn_rcpf(1.0f + e);
    return copysignf(t, x);
}

// ---------------------------------------------------------------------------
// Kernel A: input projections (fp32). Stages xz+bz+cz -> d_ws,
// xh+bh+ch -> d_out (U-side biases folded in; consumed in place by rec).
// ---------------------------------------------------------------------------
__global__ __launch_bounds__(256) void proj_kernel(
    const float* __restrict__ x,
    const float* __restrict__ Wz, const float* __restrict__ bz,
    const float* __restrict__ Wh, const float* __restrict__ bh,
    const float* __restrict__ cz, const float* __restrict__ ch,
    float* __restrict__ xz_out,   // d_ws
    float* __restrict__ xh_out)   // d_out (outputs region)
{
    const int tid  = threadIdx.x;
    const int row0 = blockIdx.x * 32;

    float accz[32];
    float acch[32];
    const float bzv = bz[tid] + cz[tid];
    const float bhv = bh[tid] + ch[tid];
#pragma unroll
    for (int r = 0; r < 32; ++r) { accz[r] = bzv; acch[r] = bhv; }

    const float* wzr = Wz + tid * IN;
    const float* whr = Wh + tid * IN;

    for (int k4 = 0; k4 < IN / 4; ++k4) {
        const float4 wz = *reinterpret_cast<const float4*>(wzr + k4 * 4);
        const float4 wh = *reinterpret_cast<const float4*>(whr + k4 * 4);
#pragma unroll
        for (int r = 0; r < 32; ++r) {
            const float4 xv = *reinterpret_cast<const float4*>(
                x + (size_t)(row0 + r) * IN + k4 * 4);
            accz[r] += xv.x * wz.x + xv.y * wz.y + xv.z * wz.z + xv.w * wz.w;
            acch[r] += xv.x * wh.x + xv.y * wh.y + xv.z * wh.z + xv.w * wh.w;
        }
    }

#pragma unroll
    for (int r = 0; r < 32; ++r) {
        const size_t o = (size_t)(row0 + r) * HID + tid;
        xz_out[o] = accz[r];
        xh_out[o] = acch[r];
    }
}

// ---------------------------------------------------------------------------
// Kernel B: recurrence. 512 thr/WG, one WG per batch. Register-resident fp16
// U (128 VGPRs), fp32 dot2 accumulate, skewed fp16 h in LDS (conflict-free
// ds_read_b128), all-lane fast-math epilogue, 1 barrier/step.
// Thread (og=tid>>2, ks=tid&3): outputs {og, og+128}, k in [64ks, 64ks+64).
// h state exact fp32, replicated across the 4 ks lanes.
// ---------------------------------------------------------------------------
__global__ __launch_bounds__(512) void rec_kernel(
    const float* __restrict__ hidden0,
    const float* __restrict__ Uz,
    const float* __restrict__ Uh,
    const float* __restrict__ xz_in,
    float* __restrict__ out,
    float* __restrict__ h_final)
{
    const int b   = blockIdx.x;
    const int tid = threadIdx.x;
    const int og  = tid >> 2;
    const int ks  = tid & 3;
    const int o0  = og;
    const int o1  = og + 128;
    const int k0  = ks * 64;

    // skewed fp16 h, double buffered: addr(k) = k + (k>>5)*8 halves
    __shared__ __align__(16) _Float16 hbuf[2][320];

    hf2 uz0[32], uz1[32], uh0[32], uh1[32];
    {
        const float* pz0 = Uz + o0 * HID + k0;
        const float* pz1 = Uz + o1 * HID + k0;
        const float* ph0 = Uh + o0 * HID + k0;
        const float* ph1 = Uh + o1 * HID + k0;
#pragma unroll
        for (int i = 0; i < 16; ++i) {
            float4 v;
            v = *reinterpret_cast<const float4*>(pz0 + 4 * i);
            uz0[2*i]   = hf2{(_Float16)v.x, (_Float16)v.y};
            uz0[2*i+1] = hf2{(_Float16)v.z, (_Float16)v.w};
            v = *reinterpret_cast<const float4*>(pz1 + 4 * i);
            uz1[2*i]   = hf2{(_Float16)v.x, (_Float16)v.y};
            uz1[2*i+1] = hf2{(_Float16)v.z, (_Float16)v.w};
            v = *reinterpret_cast<const float4*>(ph0 + 4 * i);
            uh0[2*i]   = hf2{(_Float16)v.x, (_Float16)v.y};
            uh0[2*i+1] = hf2{(_Float16)v.z, (_Float16)v.w};
            v = *reinterpret_cast<const float4*>(ph1 + 4 * i);
            uh1[2*i]   = hf2{(_Float16)v.x, (_Float16)v.y};
            uh1[2*i+1] = hf2{(_Float16)v.z, (_Float16)v.w};
        }
    }

    float h0 = hidden0[b * HID + o0];
    float h1 = hidden0[b * HID + o1];
    if (tid < 256) {
        hbuf[0][tid + (tid >> 5) * 8] = (_Float16)hidden0[b * HID + tid];
    }
    __syncthreads();

#define REC_STEP(CUR, NXT, T)                                                  \
    {                                                                          \
        const size_t base = ((size_t)(T) * BATCH + b) * HID;                   \
        const float xz0 = xz_in[base + o0];                                    \
        const float xz1 = xz_in[base + o1];                                    \
        const float xh0 = out[base + o0];                                      \
        const float xh1 = out[base + o1];                                      \
        float accz0 = 0.f, accz1 = 0.f, acch0 = 0.f, acch1 = 0.f;              \
        const _Float16* hpA = &hbuf[CUR][80 * ks];                             \
        _Pragma("unroll")                                                      \
        for (int c = 0; c < 8; ++c) {                                          \
            const int off = 8 * c + ((c >= 4) ? 8 : 0); /* skip skew gap */    \
            const hf8 hv = *reinterpret_cast<const hf8*>(hpA + off);           \
            const hf2 p0 = __builtin_shufflevector(hv, hv, 0, 1);              \
            const hf2 p1 = __builtin_shufflevector(hv, hv, 2, 3);              \
            const hf2 p2 = __builtin_shufflevector(hv, hv, 4, 5);              \
            const hf2 p3 = __builtin_shufflevector(hv, hv, 6, 7);              \
            accz0 = dot2(p0, uz0[4*c+0], accz0);                               \
            accz0 = dot2(p1, uz0[4*c+1], accz0);                               \
            accz0 = dot2(p2, uz0[4*c+2], accz0);                               \
            accz0 = dot2(p3, uz0[4*c+3], accz0);                               \
            accz1 = dot2(p0, uz1[4*c+0], accz1);                               \
            accz1 = dot2(p1, uz1[4*c+1], accz1);                               \
            accz1 = dot2(p2, uz1[4*c+2], accz1);                               \
            accz1 = dot2(p3, uz1[4*c+3], accz1);                               \
            acch0 = dot2(p0, uh0[4*c+0], acch0);                               \
            acch0 = dot2(p1, uh0[4*c+1], acch0);                               \
            acch0 = dot2(p2, uh0[4*c+2], acch0);                               \
            acch0 = dot2(p3, uh0[4*c+3], acch0);                               \
            acch1 = dot2(p0, uh1[4*c+0], acch1);                               \
            acch1 = dot2(p1, uh1[4*c+1], acch1);                               \
            acch1 = dot2(p2, uh1[4*c+2], acch1);                               \
            acch1 = dot2(p3, uh1[4*c+3], acch1);                               \
        }                                                                      \
        accz0 += __shfl_xor(accz0, 1); accz0 += __shfl_xor(accz0, 2);          \
        accz1 += __shfl_xor(accz1, 1); accz1 += __shfl_xor(accz1, 2);          \
        acch0 += __shfl_xor(acch0, 1); acch0 += __shfl_xor(acch0, 2);          \
        acch1 += __shfl_xor(acch1, 1); acch1 += __shfl_xor(acch1, 2);          \
        const float z0 = fast_sigmoid(accz0 + xz0);                            \
        const float z1 = fast_sigmoid(accz1 + xz1);                            \
        const float t0 = fast_tanh(acch0 + xh0);                               \
        const float t1 = fast_tanh(acch1 + xh1);                               \
        h0 = fmaf(z0, t0 - h0, h0);                                            \
        h1 = fmaf(z1, t1 - h1, h1);                                            \
        if (ks == 0) {                                                         \
            out[base + o0] = h0;                                               \
            out[base + o1] = h1;                                               \
            hbuf[NXT][o0 + (o0 >> 5) * 8] = (_Float16)h0;                      \
            hbuf[NXT][o1 + (o1 >> 5) * 8] = (_Float16)h1;                      \
        }                                                                      \
        __syncthreads();                                                       \
    }

    for (int t = 0; t < SEQ; t += 2) {
        REC_STEP(0, 1, t)
        REC_STEP(1, 0, t + 1)
    }
#undef REC_STEP

    if (ks == 0) {
        h_final[b * HID + o0] = h0;
        h_final[b * HID + o1] = h1;
    }
}

extern "C" void kernel_launch(void* const* d_in, const int* in_sizes, int n_in,
                              void* d_out, int out_size, void* d_ws, size_t ws_size,
                              hipStream_t stream) {
    const float* x      = (const float*)d_in[0];
    const float* hidden = (const float*)d_in[1];
    const float* Wz     = (const float*)d_in[2];
    const float* bz     = (const float*)d_in[3];
    const float* Uz     = (const float*)d_in[4];
    const float* cz     = (const float*)d_in[5];
    const float* Wh     = (const float*)d_in[6];
    const float* bh     = (const float*)d_in[7];
    const float* Uh     = (const float*)d_in[8];
    const float* ch     = (const float*)d_in[9];

    float* out     = (float*)d_out;                        // [SEQ*BATCH*HID]
    float* h_final = out + (size_t)SEQ * BATCH * HID;      // [BATCH*HID]
    float* xz_ws   = (float*)d_ws;                         // 128 MiB

    proj_kernel<<<(SEQ * BATCH) / 32, 256, 0, stream>>>(
        x, Wz, bz, Wh, bh, cz, ch, xz_ws, out);

    rec_kernel<<<BATCH, 512, 0, stream>>>(
        hidden, Uz, Uh, xz_ws, out, h_final);
}

// Round 4
// 2522.688 us; speedup vs baseline: 12.4032x; 1.1151x over previous
//
#include <hip/hip_runtime.h>
#include <math.h>

#define SEQ   2048
#define BATCH 64
#define IN    256
#define HID   256

typedef _Float16 hf2 __attribute__((ext_vector_type(2)));
typedef _Float16 hf8 __attribute__((ext_vector_type(8)));
typedef float    f32x4 __attribute__((ext_vector_type(4)));

static __device__ __forceinline__ float dot2(hf2 a, hf2 b, float c) {
#if __has_builtin(__builtin_amdgcn_fdot2)
    return __builtin_amdgcn_fdot2(a, b, c, false);
#else
    return fmaf((float)a.x, (float)b.x, fmaf((float)a.y, (float)b.y, c));
#endif
}

static __device__ __forceinline__ float fast_sigmoid(float x) {
    return __builtin_amdgcn_rcpf(1.0f + __expf(-x));
}

static __device__ __forceinline__ float fast_tanh(float x) {
    const float e = __expf(-2.0f * fabsf(x));
    const float t = (1.0f - e) * __builtin_amdgcn_rcpf(1.0f + e);
    return copysignf(t, x);
}

// ---------------------------------------------------------------------------
// Kernel 0: convert Wz,Wh (fp32, [256][256] each) -> W16 [512][256] fp16.
// Rows 0-255 = Wz, rows 256-511 = Wh.
// ---------------------------------------------------------------------------
__global__ __launch_bounds__(256) void w16_kernel(
    const float* __restrict__ Wz, const float* __restrict__ Wh,
    _Float16* __restrict__ W16)
{
    const int idx = blockIdx.x * 256 + threadIdx.x;   // 0 .. 512*256-1
    const int row = idx >> 8;
    const int col = idx & 255;
    const float v = (row < 256) ? Wz[row * 256 + col] : Wh[(row - 256) * 256 + col];
    W16[idx] = (_Float16)v;
}

// ---------------------------------------------------------------------------
// Kernel A: input projections via mfma_f32_16x16x32_f16.
// WG = 256 thr (4 waves), one 16-row M-tile, N=512 split 128 cols/wave:
// waves 0-1 -> z-cols [0,256) -> xz16 (fp16, d_ws); waves 2-3 -> h-cols ->
// xh fp32 staged into d_out (consumed in place by rec).
// Fragments: A/B lane l: row/col = l&15, k = 8*(l>>4)+j (contiguous 16B).
// C/D: col = l&15, row = 4*(l>>4)+reg [m89-verified].
// Biases (b + c folded) added in epilogue.
// ---------------------------------------------------------------------------
__global__ __launch_bounds__(256) void proj_mfma_kernel(
    const float* __restrict__ x,
    const _Float16* __restrict__ W16,
    const float* __restrict__ bz, const float* __restrict__ cz,
    const float* __restrict__ bh, const float* __restrict__ ch,
    _Float16* __restrict__ xz16,   // d_ws [SEQ*BATCH][256] fp16
    float* __restrict__ xh_out)    // d_out [SEQ*BATCH][256] fp32
{
    const int tid  = threadIdx.x;
    const int lane = tid & 63;
    const int w    = tid >> 6;            // wave 0..3
    const int m0   = blockIdx.x * 16;     // global row tile
    const int col0 = w * 128;             // global col base [0,512)

    const int r = lane & 15;              // A-row / B-col / C-col
    const int g = lane >> 4;              // k-group 0..3

    f32x4 acc[8] = {f32x4{0,0,0,0}, f32x4{0,0,0,0}, f32x4{0,0,0,0}, f32x4{0,0,0,0},
                    f32x4{0,0,0,0}, f32x4{0,0,0,0}, f32x4{0,0,0,0}, f32x4{0,0,0,0}};

    const float*     xrow  = x   + (size_t)(m0 + r) * IN + g * 8;
    const _Float16*  wbase = W16 + (size_t)(col0 + r) * IN + g * 8;

#pragma unroll
    for (int kt = 0; kt < 8; ++kt) {
        // A fragment: 8 consecutive fp32 of this row -> fp16 (RTE)
        const float4 xa = *reinterpret_cast<const float4*>(xrow + kt * 32);
        const float4 xb = *reinterpret_cast<const float4*>(xrow + kt * 32 + 4);
        hf8 a;
        a[0] = (_Float16)xa.x; a[1] = (_Float16)xa.y;
        a[2] = (_Float16)xa.z; a[3] = (_Float16)xa.w;
        a[4] = (_Float16)xb.x; a[5] = (_Float16)xb.y;
        a[6] = (_Float16)xb.z; a[7] = (_Float16)xb.w;
#pragma unroll
        for (int t = 0; t < 8; ++t) {
            const hf8 bfrag = *reinterpret_cast<const hf8*>(
                wbase + (size_t)t * 16 * IN + kt * 32);
            acc[t] = __builtin_amdgcn_mfma_f32_16x16x32_f16(a, bfrag, acc[t], 0, 0, 0);
        }
    }

    if (w < 2) {
#pragma unroll
        for (int t = 0; t < 8; ++t) {
            const int c = col0 + t * 16 + r;            // z-col 0..255
            const float bsum = bz[c] + cz[c];
#pragma unroll
            for (int reg = 0; reg < 4; ++reg) {
                const int m = m0 + 4 * g + reg;
                xz16[(size_t)m * HID + c] = (_Float16)(acc[t][reg] + bsum);
            }
        }
    } else {
#pragma unroll
        for (int t = 0; t < 8; ++t) {
            const int c = col0 - 256 + t * 16 + r;      // h-col 0..255
            const float bsum = bh[c] + ch[c];
#pragma unroll
            for (int reg = 0; reg < 4; ++reg) {
                const int m = m0 + 4 * g + reg;
                xh_out[(size_t)m * HID + c] = acc[t][reg] + bsum;
            }
        }
    }
}

// ---------------------------------------------------------------------------
// Kernel B: recurrence. 1024 thr/WG (16 waves, 4/SIMD), one WG per batch.
// Thread (og = tid>>3, ks = tid&7): outputs {og, og+128}, k in [32ks,32ks+32).
// U register-resident fp16 (64 VGPRs), fp32 dot2 accumulate. h operand fp16
// in LDS, double-buffered, skew: addr(k) = k + (k>>5)*8 halves -> the 8
// ks-slices' ds_read_b128 start at dword-banks {0,20,8,28,16,4,24,12} —
// conflict-free, 16B-aligned. All 8 ks-lanes of an og are lanes of ONE wave,
// so the read-xh / write-h race on out[] is ordered by wave program order.
// 1 barrier/step. h state exact fp32, replicated across ks lanes.
// ---------------------------------------------------------------------------
__global__ __launch_bounds__(1024) void rec_kernel(
    const float* __restrict__ hidden0,
    const float* __restrict__ Uz,
    const float* __restrict__ Uh,
    const _Float16* __restrict__ xz16,  // d_ws: Wz x + bz + cz (fp16)
    float* __restrict__ out,            // d_out: xh staged, h out
    float* __restrict__ h_final)        // d_out + SEQ*BATCH*HID
{
    const int b   = blockIdx.x;
    const int tid = threadIdx.x;
    const int og  = tid >> 3;     // 0..127
    const int ks  = tid & 7;      // 0..7
    const int o0  = og;
    const int o1  = og + 128;
    const int k0  = ks * 32;

    // skewed fp16 h, double buffered: addr(k) = k + (k>>5)*8 halves
    __shared__ __align__(16) _Float16 hbuf[2][320];

    // ---- hoist U into registers: 2 mats x 2 outputs x 32 halves ----
    hf2 uz0[16], uz1[16], uh0[16], uh1[16];
    {
        const float* pz0 = Uz + o0 * HID + k0;
        const float* pz1 = Uz + o1 * HID + k0;
        const float* ph0 = Uh + o0 * HID + k0;
        const float* ph1 = Uh + o1 * HID + k0;
#pragma unroll
        for (int i = 0; i < 8; ++i) {
            float4 v;
            v = *reinterpret_cast<const float4*>(pz0 + 4 * i);
            uz0[2*i]   = hf2{(_Float16)v.x, (_Float16)v.y};
            uz0[2*i+1] = hf2{(_Float16)v.z, (_Float16)v.w};
            v = *reinterpret_cast<const float4*>(pz1 + 4 * i);
            uz1[2*i]   = hf2{(_Float16)v.x, (_Float16)v.y};
            uz1[2*i+1] = hf2{(_Float16)v.z, (_Float16)v.w};
            v = *reinterpret_cast<const float4*>(ph0 + 4 * i);
            uh0[2*i]   = hf2{(_Float16)v.x, (_Float16)v.y};
            uh0[2*i+1] = hf2{(_Float16)v.z, (_Float16)v.w};
            v = *reinterpret_cast<const float4*>(ph1 + 4 * i);
            uh1[2*i]   = hf2{(_Float16)v.x, (_Float16)v.y};
            uh1[2*i+1] = hf2{(_Float16)v.z, (_Float16)v.w};
        }
    }

    float h0 = hidden0[b * HID + o0];
    float h1 = hidden0[b * HID + o1];
    if (tid < 256) {
        hbuf[0][tid + (tid >> 5) * 8] = (_Float16)hidden0[b * HID + tid];
    }
    __syncthreads();

#define REC_STEP(CUR, NXT, T)                                                  \
    {                                                                          \
        const size_t base = ((size_t)(T) * BATCH + b) * HID;                   \
        const float xz0 = (float)xz16[base + o0];                              \
        const float xz1 = (float)xz16[base + o1];                              \
        const float xh0 = out[base + o0];                                      \
        const float xh1 = out[base + o1];                                      \
        float accz0 = 0.f, accz1 = 0.f, acch0 = 0.f, acch1 = 0.f;              \
        const _Float16* hp = &hbuf[CUR][40 * ks];                              \
        _Pragma("unroll")                                                      \
        for (int i = 0; i < 4; ++i) {                                          \
            const hf8 hv = *reinterpret_cast<const hf8*>(hp + 8 * i);          \
            const hf2 p0 = __builtin_shufflevector(hv, hv, 0, 1);              \
            const hf2 p1 = __builtin_shufflevector(hv, hv, 2, 3);              \
            const hf2 p2 = __builtin_shufflevector(hv, hv, 4, 5);              \
            const hf2 p3 = __builtin_shufflevector(hv, hv, 6, 7);              \
            accz0 = dot2(p0, uz0[4*i+0], accz0);                               \
            accz0 = dot2(p1, uz0[4*i+1], accz0);                               \
            accz0 = dot2(p2, uz0[4*i+2], accz0);                               \
            accz0 = dot2(p3, uz0[4*i+3], accz0);                               \
            accz1 = dot2(p0, uz1[4*i+0], accz1);                               \
            accz1 = dot2(p1, uz1[4*i+1], accz1);                               \
            accz1 = dot2(p2, uz1[4*i+2], accz1);                               \
            accz1 = dot2(p3, uz1[4*i+3], accz1);                               \
            acch0 = dot2(p0, uh0[4*i+0], acch0);                               \
            acch0 = dot2(p1, uh0[4*i+1], acch0);                               \
            acch0 = dot2(p2, uh0[4*i+2], acch0);                               \
            acch0 = dot2(p3, uh0[4*i+3], acch0);                               \
            acch1 = dot2(p0, uh1[4*i+0], acch1);                               \
            acch1 = dot2(p1, uh1[4*i+1], acch1);                               \
            acch1 = dot2(p2, uh1[4*i+2], acch1);                               \
            acch1 = dot2(p3, uh1[4*i+3], acch1);                               \
        }                                                                      \
        accz0 += __shfl_xor(accz0, 1); accz0 += __shfl_xor(accz0, 2);          \
        accz0 += __shfl_xor(accz0, 4);                                         \
        accz1 += __shfl_xor(accz1, 1); accz1 += __shfl_xor(accz1, 2);          \
        accz1 += __shfl_xor(accz1, 4);                                         \
        acch0 += __shfl_xor(acch0, 1); acch0 += __shfl_xor(acch0, 2);          \
        acch0 += __shfl_xor(acch0, 4);                                         \
        acch1 += __shfl_xor(acch1, 1); acch1 += __shfl_xor(acch1, 2);          \
        acch1 += __shfl_xor(acch1, 4);                                         \
        const float z0 = fast_sigmoid(accz0 + xz0);                            \
        const float z1 = fast_sigmoid(accz1 + xz1);                            \
        const float t0 = fast_tanh(acch0 + xh0);                               \
        const float t1 = fast_tanh(acch1 + xh1);                               \
        h0 = fmaf(z0, t0 - h0, h0);                                            \
        h1 = fmaf(z1, t1 - h1, h1);                                            \
        if (ks == 0) {                                                         \
            out[base + o0] = h0;                                               \
            out[base + o1] = h1;                                               \
            hbuf[NXT][o0 + (o0 >> 5) * 8] = (_Float16)h0;                      \
            hbuf[NXT][o1 + (o1 >> 5) * 8] = (_Float16)h1;                      \
        }                                                                      \
        __syncthreads();                                                       \
    }

    for (int t = 0; t < SEQ; t += 2) {
        REC_STEP(0, 1, t)
        REC_STEP(1, 0, t + 1)
    }
#undef REC_STEP

    if (ks == 0) {
        h_final[b * HID + o0] = h0;
        h_final[b * HID + o1] = h1;
    }
}

extern "C" void kernel_launch(void* const* d_in, const int* in_sizes, int n_in,
                              void* d_out, int out_size, void* d_ws, size_t ws_size,
                              hipStream_t stream) {
    const float* x      = (const float*)d_in[0];
    const float* hidden = (const float*)d_in[1];
    const float* Wz     = (const float*)d_in[2];
    const float* bz     = (const float*)d_in[3];
    const float* Uz     = (const float*)d_in[4];
    const float* cz     = (const float*)d_in[5];
    const float* Wh     = (const float*)d_in[6];
    const float* bh     = (const float*)d_in[7];
    const float* Uh     = (const float*)d_in[8];
    const float* ch     = (const float*)d_in[9];

    float* out     = (float*)d_out;                        // [SEQ*BATCH*HID]
    float* h_final = out + (size_t)SEQ * BATCH * HID;      // [BATCH*HID]

    _Float16* xz16 = (_Float16*)d_ws;                              // 64 MiB
    _Float16* W16  = (_Float16*)((char*)d_ws + ((size_t)64 << 20)); // 256 KiB

    // W fp32 -> fp16 (once per call)
    w16_kernel<<<512, 256, 0, stream>>>(Wz, Wh, W16);

    // Projections: xz16 -> ws, xh (fp32) -> d_out
    proj_mfma_kernel<<<(SEQ * BATCH) / 16, 256, 0, stream>>>(
        x, W16, bz, cz, bh, ch, xz16, out);

    // Sequential scan: one WG per batch element.
    rec_kernel<<<BATCH, 1024, 0, stream>>>(
        hidden, Uz, Uh, xz16, out, h_final);
}